// Round 9
// baseline (223.656 us; speedup 1.0000x reference)
//
#include <hip/hip_runtime.h>
#include <hip/hip_cooperative_groups.h>

namespace cg = cooperative_groups;

#define AS1 __attribute__((address_space(1)))
#define AS3 __attribute__((address_space(3)))

typedef unsigned short u16;
typedef _Float16 f16;
typedef __bf16 bf16x8 __attribute__((ext_vector_type(8)));
typedef float f32x4 __attribute__((ext_vector_type(4)));
typedef _Float16 f16x4 __attribute__((ext_vector_type(4)));
typedef unsigned short u16x8 __attribute__((ext_vector_type(8)));

// Single cooperative kernel, 256 WGs x 512 thr (1 WG/CU).
// ws layout (20 MB):
//   A: [4][512][1024]  bf16(u16) @ 0      (4 MB)
//   W: [4][1024][1024] bf16(u16) @ 4 MB   (8 MB)
//   P: [8][512][1024]  f16       @ 12 MB  (8 MB)
// XCD-affinity: WG bid -> XCD bid%8 (heuristic). W slice (nb,kz) is prepped by
// the 4 WGs (mb=0..3) that consume it (all bid%8==nb); P partials of tile
// (mb,nb) are written and reduced by WGs with bid%8==nb. L2-local by design.

__device__ __forceinline__ u16 f2bf(float f) {
    union { float f; unsigned int u; } v;
    v.f = f;
    unsigned int u = v.u;
    u += 0x7fffu + ((u >> 16) & 1u);   // RNE
    return (u16)(u >> 16);
}

__device__ __forceinline__ void load16(const u16* g, u16* l) {
    __builtin_amdgcn_global_load_lds((const AS1 unsigned int*)g,
                                     (AS3 unsigned int*)l, 16, 0, 0);
}

__global__ __launch_bounds__(512) void fused_kernel(
    const float* __restrict__ x,
    const float* __restrict__ cp0, const float* __restrict__ cp1,
    const float* __restrict__ cp2, const float* __restrict__ cp3,
    u16* __restrict__ A, u16* __restrict__ W,
    f16* __restrict__ P, float* __restrict__ out)
{
    __shared__ u16 lsA[2][128 * 128];   // 32 KB per buf
    __shared__ u16 lsB[2][128 * 128];

    const int tid  = threadIdx.x;
    const int lane = tid & 63;
    const int wid  = tid >> 6;

    const int bid  = blockIdx.x;          // 0..255
    const int nb   = bid & 7;             // N-block (XCD key)
    const int mb   = (bid >> 3) & 3;      // M-block
    const int kz   = bid >> 5;            // K-slice 0..7
    const int seg  = kz >> 1;
    const int kbase = (kz & 1) * 512;
    const int brow = mb * 128;
    const int bcol = nb * 128;

    const float* cps[4] = {cp0, cp1, cp2, cp3};

    // ================= Phase A: prep (W slice we will consume + A share) =====
    {
        // W: slice (nb,kz) = cp[seg] rows [bcol,bcol+128) k [kbase,kbase+512).
        // This WG writes 32 of those rows (its mb quarter). 512 thr:
        // row_local = tid>>4 (0..31), 16 thr/row x 32 k-elems each.
        const int rr  = bcol + mb * 32 + (tid >> 4);
        const int kk0 = kbase + (tid & 15) * 32;
        const float* src = cps[seg] + rr * 1024 + kk0;
        u16* dst = W + seg * 1048576 + rr * 1024 + kk0;
        #pragma unroll
        for (int c = 0; c < 4; ++c) {
            float4 v0 = *(const float4*)(src + c * 8);
            float4 v1 = *(const float4*)(src + c * 8 + 4);
            u16x8 o;
            o[0] = f2bf(v0.x); o[1] = f2bf(v0.y); o[2] = f2bf(v0.z); o[3] = f2bf(v0.w);
            o[4] = f2bf(v1.x); o[5] = f2bf(v1.y); o[6] = f2bf(v1.z); o[7] = f2bf(v1.w);
            *(u16x8*)(dst + c * 8) = o;
        }
        // A: flat share, 2048 x-elems per WG, 4 per thread.
        const int idx = bid * 2048 + tid * 4;
        float4 v = *(const float4*)(x + idx);
        float vv[4] = {v.x, v.y, v.z, v.w};
        u16 q[4][4];
        #pragma unroll
        for (int j = 0; j < 4; ++j) {
            float xx = vv[j];
            float t = fminf(fabsf(xx), 1.0f);
            float s = 1.0f - t;
            q[0][j] = f2bf(s * s * s * xx);
            q[1][j] = f2bf(3.0f * s * s * t * xx);
            q[2][j] = f2bf(3.0f * s * t * t * xx);
            q[3][j] = f2bf(t * t * t * xx);
        }
        #pragma unroll
        for (int sg = 0; sg < 4; ++sg) {
            ushort4 o; o.x = q[sg][0]; o.y = q[sg][1]; o.z = q[sg][2]; o.w = q[sg][3];
            *(ushort4*)(A + sg * 524288 + idx) = o;
        }
    }

    __threadfence();
    cg::this_grid().sync();

    // ================= Phase B: GEMM (r8 structure, counted vmcnt) ===========
    {
        const u16* Ag = A + seg * 524288  + brow * 1024 + kbase;
        const u16* Wg = W + seg * 1048576 + bcol * 1024 + kbase;

        int goff[4], loff[4];
        #pragma unroll
        for (int j = 0; j < 4; ++j) {
            const int c   = tid + j * 512;
            const int row = c >> 4;
            goff[j] = row * 1024 + ((c & 15) ^ (row & 15)) * 8;
            loff[j] = c * 8;
        }

        const int wr = (wid >> 2) * 64;
        const int wc = (wid & 3) * 32;
        const int fr = lane & 15;
        const int q  = lane >> 4;
        int ofs[4];
        #pragma unroll
        for (int kk = 0; kk < 4; ++kk)
            ofs[kk] = ((kk * 4 + q) ^ fr) * 16;

        f32x4 acc[4][2] = {};

        #pragma unroll
        for (int j = 0; j < 4; ++j) {
            load16(Ag + goff[j], &lsA[0][loff[j]]);
            load16(Wg + goff[j], &lsB[0][loff[j]]);
        }

        #pragma unroll
        for (int kt = 0; kt < 4; ++kt) {
            const int buf = kt & 1;
            if (kt < 3) {
                const int k0 = (kt + 1) * 128;
                #pragma unroll
                for (int j = 0; j < 4; ++j) {
                    load16(Ag + k0 + goff[j], &lsA[buf ^ 1][loff[j]]);
                    load16(Wg + k0 + goff[j], &lsB[buf ^ 1][loff[j]]);
                }
                asm volatile("s_waitcnt vmcnt(8)" ::: "memory");
            } else {
                asm volatile("s_waitcnt vmcnt(0)" ::: "memory");
            }
            __builtin_amdgcn_s_barrier();
            __builtin_amdgcn_sched_barrier(0);

            const char* bA = (const char*)lsA[buf];
            const char* bB = (const char*)lsB[buf];
            #pragma unroll
            for (int kk = 0; kk < 4; ++kk) {
                bf16x8 a[4], b[2];
                #pragma unroll
                for (int m = 0; m < 4; ++m)
                    a[m] = *(const bf16x8*)(bA + (wr + m * 16 + fr) * 256 + ofs[kk]);
                #pragma unroll
                for (int n = 0; n < 2; ++n)
                    b[n] = *(const bf16x8*)(bB + (wc + n * 16 + fr) * 256 + ofs[kk]);
                #pragma unroll
                for (int m = 0; m < 4; ++m)
                    #pragma unroll
                    for (int n = 0; n < 2; ++n)
                        acc[m][n] = __builtin_amdgcn_mfma_f32_16x16x32_bf16(
                            a[m], b[n], acc[m][n], 0, 0, 0);
            }
            __builtin_amdgcn_s_barrier();
            __builtin_amdgcn_sched_barrier(0);
        }

        // f16 partials; C/D layout col=lane&15, row=(lane>>4)*4+j
        f16* Pk = P + kz * 524288;
        const int cr0 = brow + wr + q * 4;
        const int cc0 = bcol + wc + fr;
        #pragma unroll
        for (int m = 0; m < 4; ++m)
            #pragma unroll
            for (int n = 0; n < 2; ++n)
                #pragma unroll
                for (int j = 0; j < 4; ++j)
                    Pk[(cr0 + m * 16 + j) * 1024 + cc0 + n * 16] = (f16)acc[m][n][j];
    }

    __threadfence();
    cg::this_grid().sync();

    // ================= Phase C: reduce (local-L2: bid%8 == nb) ===============
    {
        // WG (kz,mb,nb) reduces rows [kz*16, kz*16+16) of tile (mb,nb).
        const int r   = brow + kz * 16 + (tid >> 5);
        const int c   = (tid & 31) * 4;
        const int off = r * 1024 + bcol + c;
        float s0 = 0.f, s1 = 0.f, s2 = 0.f, s3 = 0.f;
        #pragma unroll
        for (int z = 0; z < 8; ++z) {      // fixed order: deterministic
            f16x4 v = *(const f16x4*)(P + z * 524288 + off);
            s0 += (float)v[0]; s1 += (float)v[1];
            s2 += (float)v[2]; s3 += (float)v[3];
        }
        float4 o; o.x = s0; o.y = s1; o.z = s2; o.w = s3;
        *(float4*)(out + off) = o;
    }
}

extern "C" void kernel_launch(void* const* d_in, const int* in_sizes, int n_in,
                              void* d_out, int out_size, void* d_ws, size_t ws_size,
                              hipStream_t stream)
{
    const float* x   = (const float*)d_in[0];
    const float* cp0 = (const float*)d_in[1];
    const float* cp1 = (const float*)d_in[2];
    const float* cp2 = (const float*)d_in[3];
    const float* cp3 = (const float*)d_in[4];

    u16*   A   = (u16*)d_ws;
    u16*   Wb  = (u16*)((char*)d_ws + (4u << 20));
    f16*   P   = (f16*)((char*)d_ws + (12u << 20));
    float* out = (float*)d_out;

    void* args[] = {(void*)&x, (void*)&cp0, (void*)&cp1, (void*)&cp2, (void*)&cp3,
                    (void*)&A, (void*)&Wb, (void*)&P, (void*)&out};
    hipLaunchCooperativeKernel((void*)fused_kernel, dim3(256), dim3(512),
                               args, 0, stream);
}

// Round 10
// 28.922 us; speedup vs baseline: 7.7331x; 7.7331x over previous
//
#include <hip/hip_runtime.h>

#define AS1 __attribute__((address_space(1)))
#define AS3 __attribute__((address_space(3)))

typedef unsigned short u16;
typedef _Float16 f16;
typedef __bf16 bf16x8 __attribute__((ext_vector_type(8)));
typedef float f32x4 __attribute__((ext_vector_type(4)));
typedef _Float16 f16x4 __attribute__((ext_vector_type(4)));
typedef unsigned short u16x8 __attribute__((ext_vector_type(8)));

// ws layout (20 MB):
//   A: [4][512][1024]  bf16(u16) @ 0      (4 MB)   A[seg][b][i] = b_seg(x[b][i])
//   W: [4][1024][1024] bf16(u16) @ 4 MB   (8 MB)   W[seg][o][i] = bf16(cp_seg[o][i])
//   P: [8][512][1024]  f16       @ 12 MB  (8 MB)   split-K partials (f16)
//
// XCD-affinity (bid%8 -> XCD heuristic): W rows [nb*128,+128) are written ONLY
// by prep blocks with b&7==nb, and read ONLY by gemm WGs with bid&7==nb (the 32
// WGs co-located on XCD nb). P cols [nb*128,+128) written by gemm bid&7==nb,
// read by reduce blocks with bid&7==nb. Producer->consumer stays in one L2.

__device__ __forceinline__ u16 f2bf(float f) {
    union { float f; unsigned int u; } v;
    v.f = f;
    unsigned int u = v.u;
    u += 0x7fffu + ((u >> 16) & 1u);   // RNE
    return (u16)(u >> 16);
}

// 768 blocks: b<512 -> W (XCD-affine), b>=512 -> A (linear).
__global__ __launch_bounds__(256) void prep_kernel(
    const float* __restrict__ x,
    const float* __restrict__ cp0, const float* __restrict__ cp1,
    const float* __restrict__ cp2, const float* __restrict__ cp3,
    u16* __restrict__ A, u16* __restrict__ W)
{
    const int bid = blockIdx.x;
    const int tid = threadIdx.x;
    if (bid < 512) {
        // W: block (nb=b&7, c=b>>3): seg=c>>4, row-group rg=c&15.
        // Writes rows [nb*128 + rg*8, +8), k [0,1024) of W[seg].
        const int nb  = bid & 7;
        const int c   = bid >> 3;
        const int seg = c >> 4;
        const int row = nb * 128 + (c & 15) * 8 + (tid >> 5);
        const int k0  = (tid & 31) * 32;
        const float* cps[4] = {cp0, cp1, cp2, cp3};
        const float* src = cps[seg] + row * 1024 + k0;
        u16* dst = W + seg * 1048576 + row * 1024 + k0;
        #pragma unroll
        for (int cchunk = 0; cchunk < 4; ++cchunk) {
            float4 v0 = *(const float4*)(src + cchunk * 8);
            float4 v1 = *(const float4*)(src + cchunk * 8 + 4);
            u16x8 o;
            o[0] = f2bf(v0.x); o[1] = f2bf(v0.y); o[2] = f2bf(v0.z); o[3] = f2bf(v0.w);
            o[4] = f2bf(v1.x); o[5] = f2bf(v1.y); o[6] = f2bf(v1.z); o[7] = f2bf(v1.w);
            *(u16x8*)(dst + cchunk * 8) = o;
        }
    } else {
        // A: 512K elems, 8 per thread.
        const int idx = ((bid - 512) * 256 + tid) * 8;
        float4 v0 = *(const float4*)(x + idx);
        float4 v1 = *(const float4*)(x + idx + 4);
        float vv[8] = {v0.x, v0.y, v0.z, v0.w, v1.x, v1.y, v1.z, v1.w};
        u16 q[4][8];
        #pragma unroll
        for (int j = 0; j < 8; ++j) {
            float xx = vv[j];
            float t = fminf(fabsf(xx), 1.0f);
            float s = 1.0f - t;
            q[0][j] = f2bf(s * s * s * xx);
            q[1][j] = f2bf(3.0f * s * s * t * xx);
            q[2][j] = f2bf(3.0f * s * t * t * xx);
            q[3][j] = f2bf(t * t * t * xx);
        }
        #pragma unroll
        for (int seg = 0; seg < 4; ++seg) {
            u16x8 o;
            #pragma unroll
            for (int j = 0; j < 8; ++j) o[j] = q[seg][j];
            *(u16x8*)(A + seg * 524288 + idx) = o;
        }
    }
}

__device__ __forceinline__ void load16(const u16* g, u16* l) {
    __builtin_amdgcn_global_load_lds((const AS1 unsigned int*)g,
                                     (AS3 unsigned int*)l, 16, 0, 0);
}

// 128x128 tile, BK=128 (4 k-steps), split-K=8, 512 threads (8 waves of 64x32).
// Counted-vmcnt pipeline: never vmcnt(0) in the loop (T3/T4).
// LDS [128][128] bf16 XOR-swizzled: chunk (row,s) holds global (row, s^(row&15)),
// staged with pre-swizzled global source + linear LDS dest (rule #21).
__global__ __launch_bounds__(512) void gemm_kernel(
    const u16* __restrict__ A, const u16* __restrict__ W,
    f16* __restrict__ P)
{
    __shared__ u16 lsA[2][128 * 128];   // 32 KB per buf
    __shared__ u16 lsB[2][128 * 128];

    const int tid  = threadIdx.x;
    const int lane = tid & 63;
    const int wid  = tid >> 6;

    const int bid  = blockIdx.x;          // 0..255
    const int nb   = bid & 7;             // N-block == XCD key (local W slice)
    const int mb   = (bid >> 3) & 3;      // M-block
    const int kz   = bid >> 5;            // K-slice 0..7
    const int seg  = kz >> 1;
    const int kbase = (kz & 1) * 512;
    const int brow = mb * 128;
    const int bcol = nb * 128;

    const u16* Ag = A + seg * 524288  + brow * 1024 + kbase;
    const u16* Wg = W + seg * 1048576 + bcol * 1024 + kbase;

    // staging: 2048 chunks of 16B per tile; chunk c: row=c>>4, s=c&15
    int goff[4], loff[4];
    #pragma unroll
    for (int j = 0; j < 4; ++j) {
        const int c   = tid + j * 512;
        const int row = c >> 4;
        goff[j] = row * 1024 + ((c & 15) ^ (row & 15)) * 8;
        loff[j] = c * 8;
    }

    // wave sub-tile: 2(M) x 4(N); each wave 64x32
    const int wr = (wid >> 2) * 64;
    const int wc = (wid & 3) * 32;
    const int fr = lane & 15;
    const int q  = lane >> 4;
    int ofs[4];
    #pragma unroll
    for (int kk = 0; kk < 4; ++kk)
        ofs[kk] = ((kk * 4 + q) ^ fr) * 16;

    f32x4 acc[4][2] = {};

    // ---- prologue: A first (remote/LLC, long latency), then W (local L2) ----
    #pragma unroll
    for (int j = 0; j < 4; ++j)
        load16(Ag + goff[j], &lsA[0][loff[j]]);
    #pragma unroll
    for (int j = 0; j < 4; ++j)
        load16(Wg + goff[j], &lsB[0][loff[j]]);

    #pragma unroll
    for (int kt = 0; kt < 4; ++kt) {
        const int buf = kt & 1;
        if (kt < 3) {
            const int k0 = (kt + 1) * 128;
            #pragma unroll
            for (int j = 0; j < 4; ++j)
                load16(Ag + k0 + goff[j], &lsA[buf ^ 1][loff[j]]);
            #pragma unroll
            for (int j = 0; j < 4; ++j)
                load16(Wg + k0 + goff[j], &lsB[buf ^ 1][loff[j]]);
            // own 16 outstanding -> wait to <=8: previous tile landed; next
            // tile's 8 stay in flight across the barrier.
            asm volatile("s_waitcnt vmcnt(8)" ::: "memory");
        } else {
            asm volatile("s_waitcnt vmcnt(0)" ::: "memory");
        }
        __builtin_amdgcn_s_barrier();
        __builtin_amdgcn_sched_barrier(0);     // rule #18

        const char* bA = (const char*)lsA[buf];
        const char* bB = (const char*)lsB[buf];
        #pragma unroll
        for (int kk = 0; kk < 4; ++kk) {
            bf16x8 a[4], b[2];
            #pragma unroll
            for (int m = 0; m < 4; ++m)
                a[m] = *(const bf16x8*)(bA + (wr + m * 16 + fr) * 256 + ofs[kk]);
            #pragma unroll
            for (int n = 0; n < 2; ++n)
                b[n] = *(const bf16x8*)(bB + (wc + n * 16 + fr) * 256 + ofs[kk]);
            #pragma unroll
            for (int m = 0; m < 4; ++m)
                #pragma unroll
                for (int n = 0; n < 2; ++n)
                    acc[m][n] = __builtin_amdgcn_mfma_f32_16x16x32_bf16(
                        a[m], b[n], acc[m][n], 0, 0, 0);
        }
        __builtin_amdgcn_s_barrier();          // buf consumed; next iter may DMA
        __builtin_amdgcn_sched_barrier(0);
    }

    // ---- epilogue: f16 partials. C/D layout col=lane&15, row=(lane>>4)*4+j ----
    f16* Pk = P + kz * 524288;
    const int cr0 = brow + wr + q * 4;
    const int cc0 = bcol + wc + fr;
    #pragma unroll
    for (int m = 0; m < 4; ++m)
        #pragma unroll
        for (int n = 0; n < 2; ++n)
            #pragma unroll
            for (int j = 0; j < 4; ++j)
                Pk[(cr0 + m * 16 + j) * 1024 + cc0 + n * 16] = (f16)acc[m][n][j];
}

// 64 blocks, XCD-affine: block (nb=bid&7, g=bid>>3) reduces rows [g*64,+64),
// cols [nb*128,+128) -- P written by gemm WGs with the same nb (same XCD).
// Fixed z-order: bitwise deterministic.
__global__ __launch_bounds__(256) void reduce_kernel(
    const f16* __restrict__ P, float* __restrict__ out)
{
    const int nb = blockIdx.x & 7;
    const int g  = blockIdx.x >> 3;
    const int tid = threadIdx.x;
    #pragma unroll
    for (int j = 0; j < 8; ++j) {
        const int u  = tid + j * 256;            // 2048 float4-units per tile
        const int r  = g * 64 + (u >> 5);
        const int c4 = (u & 31) * 4;
        const int off = r * 1024 + nb * 128 + c4;
        float s0 = 0.f, s1 = 0.f, s2 = 0.f, s3 = 0.f;
        #pragma unroll
        for (int z = 0; z < 8; ++z) {
            f16x4 v = *(const f16x4*)(P + z * 524288 + off);
            s0 += (float)v[0]; s1 += (float)v[1];
            s2 += (float)v[2]; s3 += (float)v[3];
        }
        float4 o; o.x = s0; o.y = s1; o.z = s2; o.w = s3;
        *(float4*)(out + off) = o;
    }
}

extern "C" void kernel_launch(void* const* d_in, const int* in_sizes, int n_in,
                              void* d_out, int out_size, void* d_ws, size_t ws_size,
                              hipStream_t stream)
{
    const float* x   = (const float*)d_in[0];
    const float* cp0 = (const float*)d_in[1];
    const float* cp1 = (const float*)d_in[2];
    const float* cp2 = (const float*)d_in[3];
    const float* cp3 = (const float*)d_in[4];

    u16*   A   = (u16*)d_ws;
    u16*   Wb  = (u16*)((char*)d_ws + (4u << 20));
    f16*   P   = (f16*)((char*)d_ws + (12u << 20));
    float* out = (float*)d_out;

    prep_kernel<<<768, 256, 0, stream>>>(x, cp0, cp1, cp2, cp3, A, Wb);
    gemm_kernel<<<256, 512, 0, stream>>>(A, Wb, P);
    reduce_kernel<<<64, 256, 0, stream>>>(P, out);
}

// Round 11
// 25.817 us; speedup vs baseline: 8.6630x; 1.1202x over previous
//
#include <hip/hip_runtime.h>

#define AS1 __attribute__((address_space(1)))
#define AS3 __attribute__((address_space(3)))

typedef unsigned short u16;
typedef _Float16 f16;
typedef __bf16 bf16x8 __attribute__((ext_vector_type(8)));
typedef float f32x4 __attribute__((ext_vector_type(4)));
typedef _Float16 f16x8 __attribute__((ext_vector_type(8)));
typedef unsigned short u16x8 __attribute__((ext_vector_type(8)));

// ws layout (20 MB):
//   A: [4][512][1024]  bf16(u16) @ 0      (4 MB)   A[seg][b][i] = b_seg(x[b][i])
//   W: [4][1024][1024] bf16(u16) @ 4 MB   (8 MB)   W[seg][o][i] = bf16(cp_seg[o][i])
//   P: [8][512][1024]  f16       @ 12 MB  (8 MB)   split-K partials (f16)

__device__ __forceinline__ u16 f2bf(float f) {
    union { float f; unsigned int u; } v;
    v.f = f;
    unsigned int u = v.u;
    u += 0x7fffu + ((u >> 16) & 1u);   // RNE
    return (u16)(u >> 16);
}

// r8 prep verbatim: 16B stores, 8 elements per thread per matrix.
__global__ __launch_bounds__(256) void prep_kernel(
    const float* __restrict__ x,
    const float* __restrict__ cp0, const float* __restrict__ cp1,
    const float* __restrict__ cp2, const float* __restrict__ cp3,
    u16* __restrict__ A, u16* __restrict__ W)
{
    const int bid = blockIdx.x;
    const int tid = threadIdx.x;
    if (bid < 512) {
        const int idx = (bid * 256 + tid) * 8;
        const float* cps[4] = {cp0, cp1, cp2, cp3};
        #pragma unroll
        for (int seg = 0; seg < 4; ++seg) {
            float4 v0 = *(const float4*)(cps[seg] + idx);
            float4 v1 = *(const float4*)(cps[seg] + idx + 4);
            u16x8 o;
            o[0] = f2bf(v0.x); o[1] = f2bf(v0.y); o[2] = f2bf(v0.z); o[3] = f2bf(v0.w);
            o[4] = f2bf(v1.x); o[5] = f2bf(v1.y); o[6] = f2bf(v1.z); o[7] = f2bf(v1.w);
            *(u16x8*)(W + seg * 1048576 + idx) = o;
        }
    } else {
        const int idx = ((bid - 512) * 256 + tid) * 8;
        float4 v0 = *(const float4*)(x + idx);
        float4 v1 = *(const float4*)(x + idx + 4);
        float vv[8] = {v0.x, v0.y, v0.z, v0.w, v1.x, v1.y, v1.z, v1.w};
        u16 q[4][8];
        #pragma unroll
        for (int j = 0; j < 8; ++j) {
            float xx = vv[j];
            float t = fminf(fabsf(xx), 1.0f);
            float s = 1.0f - t;
            q[0][j] = f2bf(s * s * s * xx);
            q[1][j] = f2bf(3.0f * s * s * t * xx);
            q[2][j] = f2bf(3.0f * s * t * t * xx);
            q[3][j] = f2bf(t * t * t * xx);
        }
        #pragma unroll
        for (int seg = 0; seg < 4; ++seg) {
            u16x8 o;
            #pragma unroll
            for (int j = 0; j < 8; ++j) o[j] = q[seg][j];
            *(u16x8*)(A + seg * 524288 + idx) = o;
        }
    }
}

__device__ __forceinline__ void load16(const u16* g, u16* l) {
    __builtin_amdgcn_global_load_lds((const AS1 unsigned int*)g,
                                     (AS3 unsigned int*)l, 16, 0, 0);
}

// 128x128 tile, BK=128 (4 k-steps), split-K=8, 256 threads = 4 waves, each
// wave a FAT 64x64 sub-tile (acc[4][4]): LDS reads/step drop 192->128 KB/WG
// (operand redundancy 2x/4x -> 2x/2x) -- the k-loop is LDS-read-bound.
// Counted-vmcnt pipeline: 16 loads/thread/step, steady wait vmcnt(16).
// LDS [128][128] bf16 XOR-swizzled: chunk (row,s) holds global (row, s^(row&15)).
__global__ __launch_bounds__(256) void gemm_kernel(
    const u16* __restrict__ A, const u16* __restrict__ W,
    f16* __restrict__ P)
{
    __shared__ u16 lsA[2][128 * 128];   // 32 KB per buf
    __shared__ u16 lsB[2][128 * 128];

    const int tid  = threadIdx.x;
    const int lane = tid & 63;
    const int wid  = tid >> 6;           // 0..3

    const int bid  = blockIdx.x;          // 0..255
    const int nb   = bid & 7;             // N-block (XCD spread)
    const int mb   = (bid >> 3) & 3;      // M-block
    const int kz   = bid >> 5;            // K-slice 0..7
    const int seg  = kz >> 1;
    const int kbase = (kz & 1) * 512;
    const int brow = mb * 128;
    const int bcol = nb * 128;

    const u16* Ag = A + seg * 524288  + brow * 1024 + kbase;
    const u16* Wg = W + seg * 1048576 + bcol * 1024 + kbase;

    // staging: 2048 chunks of 16B per tile; chunk c: row=c>>4, s=c&15; 8/thread
    int goff[8], loff[8];
    #pragma unroll
    for (int j = 0; j < 8; ++j) {
        const int c   = tid + j * 256;
        const int row = c >> 4;
        goff[j] = row * 1024 + ((c & 15) ^ (row & 15)) * 8;
        loff[j] = c * 8;
    }

    // wave grid 2x2, wave tile 64x64
    const int wr = (wid >> 1) * 64;
    const int wc = (wid & 1) * 64;
    const int fr = lane & 15;
    const int q  = lane >> 4;
    int ofs[4];
    #pragma unroll
    for (int kk = 0; kk < 4; ++kk)
        ofs[kk] = ((kk * 4 + q) ^ fr) * 16;

    f32x4 acc[4][4] = {};

    // ---- prologue: issue tile 0 (16 insts/wave outstanding) ----
    #pragma unroll
    for (int j = 0; j < 8; ++j) {
        load16(Ag + goff[j], &lsA[0][loff[j]]);
        load16(Wg + goff[j], &lsB[0][loff[j]]);
    }

    #pragma unroll
    for (int kt = 0; kt < 4; ++kt) {
        const int buf = kt & 1;
        if (kt < 3) {
            const int k0 = (kt + 1) * 128;
            #pragma unroll
            for (int j = 0; j < 8; ++j) {
                load16(Ag + k0 + goff[j], &lsA[buf ^ 1][loff[j]]);
                load16(Wg + k0 + goff[j], &lsB[buf ^ 1][loff[j]]);
            }
            // 32 outstanding -> wait to <=16: previous tile landed; next
            // tile's 16 stay in flight across the barrier (T3/T4).
            asm volatile("s_waitcnt vmcnt(16)" ::: "memory");
        } else {
            asm volatile("s_waitcnt vmcnt(0)" ::: "memory");
        }
        __builtin_amdgcn_s_barrier();
        __builtin_amdgcn_sched_barrier(0);     // rule #18

        const char* bA = (const char*)lsA[buf];
        const char* bB = (const char*)lsB[buf];
        #pragma unroll
        for (int kk = 0; kk < 4; ++kk) {
            bf16x8 a[4], b[4];
            #pragma unroll
            for (int m = 0; m < 4; ++m)
                a[m] = *(const bf16x8*)(bA + (wr + m * 16 + fr) * 256 + ofs[kk]);
            #pragma unroll
            for (int n = 0; n < 4; ++n)
                b[n] = *(const bf16x8*)(bB + (wc + n * 16 + fr) * 256 + ofs[kk]);
            #pragma unroll
            for (int m = 0; m < 4; ++m)
                #pragma unroll
                for (int n = 0; n < 4; ++n)
                    acc[m][n] = __builtin_amdgcn_mfma_f32_16x16x32_bf16(
                        a[m], b[n], acc[m][n], 0, 0, 0);
        }
        __builtin_amdgcn_s_barrier();          // buf consumed; next iter may DMA
        __builtin_amdgcn_sched_barrier(0);
    }

    // ---- epilogue: f16 partials. C/D layout col=lane&15, row=(lane>>4)*4+j ----
    f16* Pk = P + kz * 524288;
    const int cr0 = brow + wr + q * 4;
    const int cc0 = bcol + wc + fr;
    #pragma unroll
    for (int m = 0; m < 4; ++m)
        #pragma unroll
        for (int n = 0; n < 4; ++n)
            #pragma unroll
            for (int j = 0; j < 4; ++j)
                Pk[(cr0 + m * 16 + j) * 1024 + cc0 + n * 16] = (f16)acc[m][n][j];
}

// r8 reduce verbatim: fixed-order 8-slice f16 sum -> f32 (deterministic).
__global__ __launch_bounds__(256) void reduce_kernel(
    const f16* __restrict__ P, float* __restrict__ out)
{
    const int idx = (blockIdx.x * 256 + threadIdx.x) * 8;
    float s[8] = {};
    #pragma unroll
    for (int z = 0; z < 8; ++z) {
        f16x8 v = *(const f16x8*)(P + z * 524288 + idx);
        #pragma unroll
        for (int e = 0; e < 8; ++e) s[e] += (float)v[e];
    }
    float4 o0, o1;
    o0.x = s[0]; o0.y = s[1]; o0.z = s[2]; o0.w = s[3];
    o1.x = s[4]; o1.y = s[5]; o1.z = s[6]; o1.w = s[7];
    *(float4*)(out + idx)     = o0;
    *(float4*)(out + idx + 4) = o1;
}

extern "C" void kernel_launch(void* const* d_in, const int* in_sizes, int n_in,
                              void* d_out, int out_size, void* d_ws, size_t ws_size,
                              hipStream_t stream)
{
    const float* x   = (const float*)d_in[0];
    const float* cp0 = (const float*)d_in[1];
    const float* cp1 = (const float*)d_in[2];
    const float* cp2 = (const float*)d_in[3];
    const float* cp3 = (const float*)d_in[4];

    u16*   A   = (u16*)d_ws;
    u16*   Wb  = (u16*)((char*)d_ws + (4u << 20));
    f16*   P   = (f16*)((char*)d_ws + (12u << 20));
    float* out = (float*)d_out;

    prep_kernel<<<768, 256, 0, stream>>>(x, cp0, cp1, cp2, cp3, A, Wb);
    gemm_kernel<<<256, 256, 0, stream>>>(A, Wb, P);
    reduce_kernel<<<256, 256, 0, stream>>>(P, out);
}